// Round 1
// baseline (137.570 us; speedup 1.0000x reference)
//
#include <hip/hip_runtime.h>

// Problem constants
#define L_SEQ 2048
#define DM 32
#define NH 2
#define FD 16
#define BH 8          // B * H
#define QT 64         // queries per block
#define ST 128        // s-tile staged in LDS
#define NW 4          // s-worker waves per block

// ---------------- Kernel A: fused QKV projection ----------------
// hs: [B*L, 32] f32. Wq/Wk/Wv: [32, 32]. Outputs q/k/v as [B, H, L, F].
__global__ __launch_bounds__(256) void qkv_proj_kernel(
    const float* __restrict__ hs, const float* __restrict__ Wq,
    const float* __restrict__ Wk, const float* __restrict__ Wv,
    float* __restrict__ q, float* __restrict__ k, float* __restrict__ v) {
  __shared__ float sW[3][32][32];
  __shared__ float sH[8][32];
  int tid = threadIdx.x;
  float* swf = &sW[0][0][0];
  for (int i = tid; i < 3072; i += 256) {
    swf[i] = (i < 1024) ? Wq[i] : (i < 2048) ? Wk[i - 1024] : Wv[i - 2048];
  }
  int row0 = blockIdx.x * 8;
  int r = tid >> 5, c = tid & 31;
  sH[r][c] = hs[(size_t)(row0 + r) * 32 + c];
  __syncthreads();
  int row = row0 + r;
  float aq = 0.f, ak = 0.f, av = 0.f;
#pragma unroll
  for (int i = 0; i < 32; i++) {
    float h = sH[r][i];
    aq += h * sW[0][i][c];
    ak += h * sW[1][i][c];
    av += h * sW[2][i][c];
  }
  // row = b*L + l ; c = h*F + f  ->  [B,H,L,F]
  int b = row >> 11, l = row & (L_SEQ - 1);
  int hh = c >> 4, f = c & 15;
  size_t idx = (((size_t)(b * NH + hh)) * L_SEQ + l) * FD + f;
  q[idx] = aq;
  k[idx] = ak;
  v[idx] = av;
}

// ---------------- Kernel B: causal quadratic-kernel attention ----------------
// q,k,v: [BH, L, F]. y: [BH, L, F].
// Block: 256 threads = 4 waves. Wave j handles s-indices sl ≡ j (mod 4) of
// each staged 128-token tile (lane-uniform s -> LDS broadcast reads).
__global__ __launch_bounds__(256) void attn_kernel(
    const float* __restrict__ q, const float* __restrict__ k,
    const float* __restrict__ v, float* __restrict__ y) {
  __shared__ float sK[ST][16];
  __shared__ float sV[ST][16];
  __shared__ float sR[QT][NW][18];  // partial acc[16] + den, padded

  int tid = threadIdx.x;
  int bh = blockIdx.y;
  int qtile = blockIdx.x;
  int j = tid >> 6;       // wave id: s-strip
  int qid = tid & 63;     // query within tile
  int t = qtile * QT + qid;

  const float* qb = q + (size_t)bh * L_SEQ * FD;
  const float* kb = k + (size_t)bh * L_SEQ * FD;
  const float* vb = v + (size_t)bh * L_SEQ * FD;

  float myq[16];
  {
    const float4* qp = (const float4*)(qb + (size_t)t * FD);
#pragma unroll
    for (int i = 0; i < 4; i++) {
      float4 f4 = qp[i];
      myq[4 * i + 0] = f4.x * 0.25f;  // fold 1/sqrt(d) into Q
      myq[4 * i + 1] = f4.y * 0.25f;
      myq[4 * i + 2] = f4.z * 0.25f;
      myq[4 * i + 3] = f4.w * 0.25f;
    }
  }
  float acc[16];
#pragma unroll
  for (int i = 0; i < 16; i++) acc[i] = 0.f;
  float den = 0.f;

  int ntiles = (qtile * QT + QT + ST - 1) / ST;
  for (int tile = 0; tile < ntiles; tile++) {
    int s0 = tile * ST;
    __syncthreads();
    {
      const float4* kg = (const float4*)(kb + (size_t)s0 * FD);
      const float4* vg = (const float4*)(vb + (size_t)s0 * FD);
      float4* ks = (float4*)sK;
      float4* vs = (float4*)sV;
      ks[tid] = kg[tid];
      ks[tid + 256] = kg[tid + 256];
      vs[tid] = vg[tid];
      vs[tid + 256] = vg[tid + 256];
    }
    __syncthreads();
    int smax = t - s0 + 1;
    if (smax > ST) smax = ST;
    for (int sl = j; sl < smax; sl += NW) {
      float a0 = 0.f, a1 = 0.f;
#pragma unroll
      for (int i = 0; i < 8; i++) a0 += myq[i] * sK[sl][i];
#pragma unroll
      for (int i = 8; i < 16; i++) a1 += myq[i] * sK[sl][i];
      float a = a0 + a1;
      float w = (0.5f * a + 1.f) * a + 1.f;  // 1 + a + a^2/2
      den += w;
#pragma unroll
      for (int i = 0; i < 16; i++) acc[i] += w * sV[sl][i];
    }
  }

#pragma unroll
  for (int i = 0; i < 16; i++) sR[qid][j][i] = acc[i];
  sR[qid][j][16] = den;
  __syncthreads();

  // reduction: thread -> (query q2, quad of 4 output features)
  int q2 = tid >> 2, quad = tid & 3;
  float d = sR[q2][0][16] + sR[q2][1][16] + sR[q2][2][16] + sR[q2][3][16];
  float inv = 1.f / d;
  float4 o;
  float* op = &o.x;
#pragma unroll
  for (int i = 0; i < 4; i++) {
    int ii = quad * 4 + i;
    op[i] = (sR[q2][0][ii] + sR[q2][1][ii] + sR[q2][2][ii] + sR[q2][3][ii]) * inv;
  }
  int tq = qtile * QT + q2;
  *(float4*)(y + ((size_t)bh * L_SEQ + tq) * FD + quad * 4) = o;
}

// ---------------- Kernel C: output projection ----------------
// y: [B,H,L,F] -> rows (b,l) of 32 channels (h*F+f) @ Wo[32,32] -> out [B*L, 32]
__global__ __launch_bounds__(256) void out_proj_kernel(
    const float* __restrict__ y, const float* __restrict__ Wo,
    float* __restrict__ out) {
  __shared__ float sW[32][32];
  __shared__ float sY[8][32];
  int tid = threadIdx.x;
  for (int i = tid; i < 1024; i += 256) (&sW[0][0])[i] = Wo[i];
  int row0 = blockIdx.x * 8;
  int r = tid >> 5, c = tid & 31;
  int row = row0 + r;  // b*L + l
  int b = row >> 11, l = row & (L_SEQ - 1);
  int hh = c >> 4, f = c & 15;
  sY[r][c] = y[(((size_t)(b * NH + hh)) * L_SEQ + l) * FD + f];
  __syncthreads();
  float acc = 0.f;
#pragma unroll
  for (int i = 0; i < 32; i++) acc += sY[r][i] * sW[i][c];
  out[(size_t)row * 32 + c] = acc;
}

extern "C" void kernel_launch(void* const* d_in, const int* in_sizes, int n_in,
                              void* d_out, int out_size, void* d_ws, size_t ws_size,
                              hipStream_t stream) {
  const float* hs = (const float*)d_in[0];
  const float* Wq = (const float*)d_in[1];
  const float* Wk = (const float*)d_in[2];
  const float* Wv = (const float*)d_in[3];
  const float* Wo = (const float*)d_in[4];
  float* out = (float*)d_out;

  float* ws = (float*)d_ws;
  const size_t PER = (size_t)BH * L_SEQ * FD;  // 262144 floats = 1 MB
  float* q = ws;
  float* k = ws + PER;
  float* v = ws + 2 * PER;
  float* y = ws + 3 * PER;

  qkv_proj_kernel<<<1024, 256, 0, stream>>>(hs, Wq, Wk, Wv, q, k, v);
  attn_kernel<<<dim3(L_SEQ / QT, BH), 256, 0, stream>>>(q, k, v, y);
  out_proj_kernel<<<1024, 256, 0, stream>>>(y, Wo, out);
}

// Round 2
// 121.550 us; speedup vs baseline: 1.1318x; 1.1318x over previous
//
#include <hip/hip_runtime.h>

// Problem constants
#define L_SEQ 2048
#define DM 32
#define NH 2
#define FD 16
#define BH 8            // B * H
#define QTW 128         // queries per tile (phase A/B)
#define SCW 128         // s per chunk
#define NQT (L_SEQ / QTW)   // 16
#define NSC (L_SEQ / SCW)   // 16

// ---------------- Kernel A: fused QKV projection ----------------
// hs: [B*L, 32]. Wq/Wk/Wv: [32,32]. Outputs q/k/v as [BH, L, F].
__global__ __launch_bounds__(256) void qkv_proj_kernel(
    const float* __restrict__ hs, const float* __restrict__ Wq,
    const float* __restrict__ Wk, const float* __restrict__ Wv,
    float* __restrict__ q, float* __restrict__ k, float* __restrict__ v) {
  __shared__ float sW[3][32][32];
  __shared__ float sH[32][32];
  int tid = threadIdx.x;
  float* swf = &sW[0][0][0];
  for (int i = tid; i < 3072; i += 256)
    swf[i] = (i < 1024) ? Wq[i] : (i < 2048) ? Wk[i - 1024] : Wv[i - 2048];
  int row0 = blockIdx.x * 32;
  int r0 = tid >> 5, c = tid & 31;
  for (int p = 0; p < 4; p++) {
    int r = r0 + p * 8;
    sH[r][c] = hs[(size_t)(row0 + r) * 32 + c];
  }
  __syncthreads();
  int hh = c >> 4, f = c & 15;
  for (int p = 0; p < 4; p++) {
    int r = r0 + p * 8;
    float aq = 0.f, ak = 0.f, av = 0.f;
#pragma unroll
    for (int i = 0; i < 32; i++) {
      float h = sH[r][i];
      aq += h * sW[0][i][c];
      ak += h * sW[1][i][c];
      av += h * sW[2][i][c];
    }
    int row = row0 + r;
    int b = row >> 11, l = row & (L_SEQ - 1);
    size_t idx = (((size_t)(b * NH + hh)) * L_SEQ + l) * FD + f;
    q[idx] = aq;
    k[idx] = ak;
    v[idx] = av;
  }
}

// ---------------- Kernel B: balanced partial attention ----------------
// Block (qt, sc, bh) computes partial (num[16], den) for 128 queries of
// tile qt against s-chunk sc. Each thread owns 2 queries (qp, qp+64) and
// strips s by wave id (lane-uniform s -> broadcast LDS reads).
// part layout: [bh][qt][sc][q(128)][17]
__global__ __launch_bounds__(256) void attn_partial_kernel(
    const float* __restrict__ q, const float* __restrict__ k,
    const float* __restrict__ v, float* __restrict__ part) {
  int qt = blockIdx.x, sc = blockIdx.y, bh = blockIdx.z;
  if (sc > qt) return;

  __shared__ float smem[8704];  // sK[0..2048) sV[2048..4096); reused as sR[4][128][17]
  float* sK = smem;
  float* sV = smem + 2048;

  int tid = threadIdx.x;
  int j = tid >> 6;    // wave id = s-strip
  int qp = tid & 63;   // query-pair id: queries qp and qp+64

  const float* kb = k + ((size_t)bh * L_SEQ + (size_t)sc * SCW) * FD;
  const float* vb = v + ((size_t)bh * L_SEQ + (size_t)sc * SCW) * FD;
  {
    const float4* kg = (const float4*)kb;
    const float4* vg = (const float4*)vb;
    float4* ks = (float4*)sK;
    float4* vs = (float4*)sV;
    ks[tid] = kg[tid];
    ks[tid + 256] = kg[tid + 256];
    vs[tid] = vg[tid];
    vs[tid + 256] = vg[tid + 256];
  }

  int t0 = qt * QTW + qp;  // first owned query
  const float* qb = q + (size_t)bh * L_SEQ * FD;
  float q0r[16], q1r[16];
  {
    const float4* p0 = (const float4*)(qb + (size_t)t0 * FD);
    const float4* p1 = (const float4*)(qb + (size_t)(t0 + 64) * FD);
#pragma unroll
    for (int i = 0; i < 4; i++) {
      float4 a = p0[i], b4 = p1[i];
      q0r[4 * i + 0] = a.x * 0.25f;  // fold 1/sqrt(d)
      q0r[4 * i + 1] = a.y * 0.25f;
      q0r[4 * i + 2] = a.z * 0.25f;
      q0r[4 * i + 3] = a.w * 0.25f;
      q1r[4 * i + 0] = b4.x * 0.25f;
      q1r[4 * i + 1] = b4.y * 0.25f;
      q1r[4 * i + 2] = b4.z * 0.25f;
      q1r[4 * i + 3] = b4.w * 0.25f;
    }
  }
  __syncthreads();

  float acc0[16], acc1[16], den0 = 0.f, den1 = 0.f;
#pragma unroll
  for (int i = 0; i < 16; i++) { acc0[i] = 0.f; acc1[i] = 0.f; }

  int m0 = t0 - sc * SCW + 1;          // causal bound for q0 (local s)
  if (m0 > SCW) m0 = SCW;
  int m1 = m0 + 64;                    // for q1 = q0 + 64
  if (m1 > SCW) m1 = SCW;

  for (int sl = j; sl < m1; sl += 4) {
    float kr[16], vr[16];
    {
      const float4* krow = (const float4*)(sK + sl * 16);
      const float4* vrow = (const float4*)(sV + sl * 16);
#pragma unroll
      for (int i = 0; i < 4; i++) {
        float4 a = krow[i];
        kr[4 * i + 0] = a.x; kr[4 * i + 1] = a.y;
        kr[4 * i + 2] = a.z; kr[4 * i + 3] = a.w;
        float4 b4 = vrow[i];
        vr[4 * i + 0] = b4.x; vr[4 * i + 1] = b4.y;
        vr[4 * i + 2] = b4.z; vr[4 * i + 3] = b4.w;
      }
    }
    float a0 = 0.f, a1 = 0.f;
#pragma unroll
    for (int i = 0; i < 16; i++) { a0 += q0r[i] * kr[i]; a1 += q1r[i] * kr[i]; }
    float w0 = (0.5f * a0 + 1.f) * a0 + 1.f;  // 1 + g + g^2/2
    float w1 = (0.5f * a1 + 1.f) * a1 + 1.f;
    w0 = (sl < m0) ? w0 : 0.f;               // mask (only diagonal chunks diverge)
    den0 += w0;
    den1 += w1;
#pragma unroll
    for (int i = 0; i < 16; i++) { acc0[i] += w0 * vr[i]; acc1[i] += w1 * vr[i]; }
  }
  __syncthreads();  // all waves done reading sK/sV

  // sR[strip j][q(128)][17]; writes stride 17 across lanes -> conflict-free
  float* sR = smem;
  {
    float* r0p = sR + j * (QTW * 17) + qp * 17;
#pragma unroll
    for (int i = 0; i < 16; i++) r0p[i] = acc0[i];
    r0p[16] = den0;
    float* r1p = sR + j * (QTW * 17) + (qp + 64) * 17;
#pragma unroll
    for (int i = 0; i < 16; i++) r1p[i] = acc1[i];
    r1p[16] = den1;
  }
  __syncthreads();

  float* po = part + (((size_t)bh * NQT + qt) * NSC + sc) * (QTW * 17);
  for (int idx = tid; idx < QTW * 17; idx += 256) {
    float s = sR[idx] + sR[QTW * 17 + idx] + sR[2 * QTW * 17 + idx] +
              sR[3 * QTW * 17 + idx];
    po[idx] = s;
  }
}

// ---------------- Kernel C: reduce partials + output projection ----------------
// Block (qt, b): for both heads reduce over sc<=qt, divide, then y @ Wo.
__global__ __launch_bounds__(256) void reduce_outproj_kernel(
    const float* __restrict__ part, const float* __restrict__ Wo,
    float* __restrict__ out) {
  int qt = blockIdx.x, b = blockIdx.y;
  __shared__ float sY[QTW][33];
  __shared__ float sWo[32][32];
  int tid = threadIdx.x;
  for (int i = tid; i < 1024; i += 256) (&sWo[0][0])[i] = Wo[i];

  int qq = tid >> 1, half = tid & 1;
  for (int h = 0; h < NH; h++) {
    int bh = b * NH + h;
    const float* po = part + (((size_t)bh * NQT + qt) * NSC) * (QTW * 17) +
                      qq * 17 + half * 8;
    float acc[8];
#pragma unroll
    for (int i = 0; i < 8; i++) acc[i] = 0.f;
    float den = 0.f;
    for (int sc = 0; sc <= qt; sc++) {
      const float* p2 = po + (size_t)sc * (QTW * 17);
#pragma unroll
      for (int i = 0; i < 8; i++) acc[i] += p2[i];
      den += p2[16 - half * 8];
    }
    float inv = 1.f / den;  // w >= 0.5 always -> den > 0
#pragma unroll
    for (int i = 0; i < 8; i++) sY[qq][h * 16 + half * 8 + i] = acc[i] * inv;
  }
  __syncthreads();

  int c = tid & 31, r0 = tid >> 5;
  float wo[32];
#pragma unroll
  for (int i = 0; i < 32; i++) wo[i] = sWo[i][c];
  for (int kk = 0; kk < 16; kk++) {
    int r = r0 + kk * 8;
    float a = 0.f;
#pragma unroll
    for (int i = 0; i < 32; i++) a += sY[r][i] * wo[i];
    out[((size_t)b * L_SEQ + qt * QTW + r) * 32 + c] = a;
  }
}

extern "C" void kernel_launch(void* const* d_in, const int* in_sizes, int n_in,
                              void* d_out, int out_size, void* d_ws, size_t ws_size,
                              hipStream_t stream) {
  const float* hs = (const float*)d_in[0];
  const float* Wq = (const float*)d_in[1];
  const float* Wk = (const float*)d_in[2];
  const float* Wv = (const float*)d_in[3];
  const float* Wo = (const float*)d_in[4];
  float* out = (float*)d_out;

  float* ws = (float*)d_ws;
  const size_t PER = (size_t)BH * L_SEQ * FD;  // 262144 floats
  float* q = ws;
  float* k = ws + PER;
  float* v = ws + 2 * PER;
  float* part = ws + 3 * PER;  // [8][16][16][128][17] f32 = ~17.8 MB

  qkv_proj_kernel<<<256, 256, 0, stream>>>(hs, Wq, Wk, Wv, q, k, v);
  attn_partial_kernel<<<dim3(NQT, NSC, BH), 256, 0, stream>>>(q, k, v, part);
  reduce_outproj_kernel<<<dim3(NQT, 4), 256, 0, stream>>>(part, Wo, out);
}

// Round 3
// 115.623 us; speedup vs baseline: 1.1898x; 1.0513x over previous
//
#include <hip/hip_runtime.h>

// Problem constants
#define L_SEQ 2048
#define DM 32
#define NH 2
#define FD 16
#define BH 8            // B * H
#define QTW 256         // queries per attn block (4 per thread)
#define SCW 128         // s per chunk
#define NQT (L_SEQ / QTW)   // 8
#define NSC (L_SEQ / SCW)   // 16

// ---------------- Kernel A: fused QKV projection ----------------
__global__ __launch_bounds__(256) void qkv_proj_kernel(
    const float* __restrict__ hs, const float* __restrict__ Wq,
    const float* __restrict__ Wk, const float* __restrict__ Wv,
    float* __restrict__ q, float* __restrict__ k, float* __restrict__ v) {
  __shared__ float sW[3][32][32];
  __shared__ float sH[32][32];
  int tid = threadIdx.x;
  float* swf = &sW[0][0][0];
  for (int i = tid; i < 3072; i += 256)
    swf[i] = (i < 1024) ? Wq[i] : (i < 2048) ? Wk[i - 1024] : Wv[i - 2048];
  int row0 = blockIdx.x * 32;
  int r0 = tid >> 5, c = tid & 31;
  for (int p = 0; p < 4; p++) {
    int r = r0 + p * 8;
    sH[r][c] = hs[(size_t)(row0 + r) * 32 + c];
  }
  __syncthreads();
  int hh = c >> 4, f = c & 15;
  for (int p = 0; p < 4; p++) {
    int r = r0 + p * 8;
    float aq = 0.f, ak = 0.f, av = 0.f;
#pragma unroll
    for (int i = 0; i < 32; i++) {
      float h = sH[r][i];
      aq += h * sW[0][i][c];
      ak += h * sW[1][i][c];
      av += h * sW[2][i][c];
    }
    int row = row0 + r;
    int b = row >> 11, l = row & (L_SEQ - 1);
    size_t idx = (((size_t)(b * NH + hh)) * L_SEQ + l) * FD + f;
    q[idx] = aq;
    k[idx] = ak;
    v[idx] = av;
  }
}

// ---------------- Kernel B: balanced partial attention ----------------
// Block x in [0,72) -> (qt, sc) with sc <= 2*qt+1; y = bh.
// 4 queries per thread (t0 + 64i); wave j handles s = j (mod 4).
// Outputs: pnum[bh][qt][sc][q 256][16], pden[bh][qt][sc][q 256].
__global__ __launch_bounds__(256, 2) void attn_partial_kernel(
    const float* __restrict__ q, const float* __restrict__ k,
    const float* __restrict__ v, float* __restrict__ pnum,
    float* __restrict__ pden) {
  __shared__ float smem[5120];  // sK[0..2048) sV[2048..4096); later sR[4][64][17]
  int tid = threadIdx.x;
  int bh = blockIdx.y;
  int x = blockIdx.x;
  int qt = 0;
  while ((qt + 1) * (qt + 2) <= x) qt++;   // <=8 scalar iters
  int sc = x - qt * (qt + 1);

  int j = tid >> 6, qp = tid & 63;
  float* sK = smem;
  float* sV = smem + 2048;
  {
    const float4* kg = (const float4*)(k + ((size_t)bh * L_SEQ + sc * SCW) * FD);
    const float4* vg = (const float4*)(v + ((size_t)bh * L_SEQ + sc * SCW) * FD);
    ((float4*)sK)[tid] = kg[tid];
    ((float4*)sK)[tid + 256] = kg[tid + 256];
    ((float4*)sV)[tid] = vg[tid];
    ((float4*)sV)[tid + 256] = vg[tid + 256];
  }

  int t0 = qt * QTW + qp;
  const float* qb = q + (size_t)bh * L_SEQ * FD;
  float qr[4][16];
#pragma unroll
  for (int i = 0; i < 4; i++) {
    const float4* p = (const float4*)(qb + (size_t)(t0 + 64 * i) * FD);
#pragma unroll
    for (int u = 0; u < 4; u++) {
      float4 f4 = p[u];
      qr[i][4 * u + 0] = f4.x * 0.25f;  // fold 1/sqrt(d)
      qr[i][4 * u + 1] = f4.y * 0.25f;
      qr[i][4 * u + 2] = f4.z * 0.25f;
      qr[i][4 * u + 3] = f4.w * 0.25f;
    }
  }
  __syncthreads();

  float acc[4][16];
  float den[4] = {0.f, 0.f, 0.f, 0.f};
#pragma unroll
  for (int i = 0; i < 4; i++)
#pragma unroll
    for (int f = 0; f < 16; f++) acc[i][f] = 0.f;

  bool full = (sc < 2 * qt);  // block fully below diagonal -> no masking
  if (full) {
    for (int sl = j; sl < SCW; sl += 4) {
      float kr[16], vr[16];
      const float4* k4 = (const float4*)(sK + sl * 16);
      const float4* v4 = (const float4*)(sV + sl * 16);
#pragma unroll
      for (int u = 0; u < 4; u++) {
        *(float4*)&kr[4 * u] = k4[u];
        *(float4*)&vr[4 * u] = v4[u];
      }
      float w[4];
#pragma unroll
      for (int i = 0; i < 4; i++) {
        float a = 0.f;
#pragma unroll
        for (int f = 0; f < 16; f++) a += qr[i][f] * kr[f];
        w[i] = (0.5f * a + 1.f) * a + 1.f;  // 1 + g + g^2/2
        den[i] += w[i];
      }
#pragma unroll
      for (int i = 0; i < 4; i++)
#pragma unroll
        for (int f = 0; f < 16; f++) acc[i][f] += w[i] * vr[f];
    }
  } else {
    int m[4];
#pragma unroll
    for (int i = 0; i < 4; i++) m[i] = t0 + 64 * i - sc * SCW + 1;
    for (int sl = j; sl < SCW; sl += 4) {
      float kr[16], vr[16];
      const float4* k4 = (const float4*)(sK + sl * 16);
      const float4* v4 = (const float4*)(sV + sl * 16);
#pragma unroll
      for (int u = 0; u < 4; u++) {
        *(float4*)&kr[4 * u] = k4[u];
        *(float4*)&vr[4 * u] = v4[u];
      }
      float w[4];
#pragma unroll
      for (int i = 0; i < 4; i++) {
        float a = 0.f;
#pragma unroll
        for (int f = 0; f < 16; f++) a += qr[i][f] * kr[f];
        float wi = (0.5f * a + 1.f) * a + 1.f;
        w[i] = (sl < m[i]) ? wi : 0.f;
        den[i] += w[i];
      }
#pragma unroll
      for (int i = 0; i < 4; i++)
#pragma unroll
        for (int f = 0; f < 16; f++) acc[i][f] += w[i] * vr[f];
    }
  }

  // 4-round strip reduction through LDS (aliased over sK/sV), then global write.
  float* sR = smem;  // [4 strips][64 q][17]
  size_t pb = ((size_t)(bh * NQT + qt) * NSC + sc) * 256;
  float* nb = pnum + pb * 16;
  float* db = pden + pb;
#pragma unroll
  for (int r = 0; r < 4; r++) {
    __syncthreads();  // prev readers of smem done
    float* dst = sR + j * 1088 + qp * 17;
#pragma unroll
    for (int i = 0; i < 16; i++) dst[i] = acc[r][i];
    dst[16] = den[r];
    __syncthreads();
#pragma unroll
    for (int e0 = 0; e0 < 1024; e0 += 256) {
      int e = e0 + tid;
      int qq = e >> 4, i = e & 15;
      int idx = qq * 17 + i;
      nb[(size_t)r * 1024 + e] =
          sR[idx] + sR[1088 + idx] + sR[2176 + idx] + sR[3264 + idx];
    }
    if (tid < 64) {
      int idx = tid * 17 + 16;
      db[r * 64 + tid] =
          sR[idx] + sR[1088 + idx] + sR[2176 + idx] + sR[3264 + idx];
    }
  }
}

// ---------------- Kernel C: reduce partials + output projection ----------------
// grid (32 q-tiles of 64, B). Thread = (q_local, f-quad).
__global__ __launch_bounds__(256) void reduce_outproj_kernel(
    const float* __restrict__ pnum, const float* __restrict__ pden,
    const float* __restrict__ Wo, float* __restrict__ out) {
  __shared__ float sY[64][33];
  __shared__ float sWo[32][32];
  int tid = threadIdx.x;
  for (int i = tid; i < 1024; i += 256) (&sWo[0][0])[i] = Wo[i];

  int ql = tid >> 2, fq = tid & 3;
  int t = blockIdx.x * 64 + ql;
  int b = blockIdx.y;
  int qt = t >> 8;          // 256-query tile
  int scm = t >> 7;         // max s-chunk (inclusive)
  int qloc = t & 255;

  for (int h = 0; h < NH; h++) {
    int bh = b * NH + h;
    size_t tb = ((size_t)(bh * NQT + qt) * NSC) * 256;
    const float* nb = pnum + (tb + qloc) * 16 + fq * 4;
    const float* db = pden + tb + qloc;
    float a0 = 0.f, a1 = 0.f, a2 = 0.f, a3 = 0.f, den = 0.f;
    for (int sc = 0; sc <= scm; sc++) {
      float4 p = *(const float4*)(nb + (size_t)sc * 256 * 16);
      a0 += p.x; a1 += p.y; a2 += p.z; a3 += p.w;
      den += db[(size_t)sc * 256];
    }
    float inv = 1.f / den;
    int cb = h * 16 + fq * 4;
    sY[ql][cb + 0] = a0 * inv;
    sY[ql][cb + 1] = a1 * inv;
    sY[ql][cb + 2] = a2 * inv;
    sY[ql][cb + 3] = a3 * inv;
  }
  __syncthreads();

  int c = tid & 31, r0 = tid >> 5;
  float wo[32];
#pragma unroll
  for (int i = 0; i < 32; i++) wo[i] = sWo[i][c];
#pragma unroll
  for (int p = 0; p < 8; p++) {
    int r = r0 + p * 8;
    float a = 0.f;
#pragma unroll
    for (int i = 0; i < 32; i++) a += sY[r][i] * wo[i];
    out[((size_t)b * L_SEQ + blockIdx.x * 64 + r) * 32 + c] = a;
  }
}

extern "C" void kernel_launch(void* const* d_in, const int* in_sizes, int n_in,
                              void* d_out, int out_size, void* d_ws, size_t ws_size,
                              hipStream_t stream) {
  const float* hs = (const float*)d_in[0];
  const float* Wq = (const float*)d_in[1];
  const float* Wk = (const float*)d_in[2];
  const float* Wv = (const float*)d_in[3];
  const float* Wo = (const float*)d_in[4];
  float* out = (float*)d_out;

  float* ws = (float*)d_ws;
  const size_t PER = (size_t)BH * L_SEQ * FD;  // 262144 floats
  float* q = ws;
  float* k = ws + PER;
  float* v = ws + 2 * PER;
  float* pnum = ws + 3 * PER;                       // 8*8*16*256*16 = 2.36M f32
  float* pden = pnum + (size_t)BH * NQT * NSC * 256 * 16;  // 147456 f32

  qkv_proj_kernel<<<256, 256, 0, stream>>>(hs, Wq, Wk, Wv, q, k, v);
  attn_partial_kernel<<<dim3(72, BH), 256, 0, stream>>>(q, k, v, pnum, pden);
  reduce_outproj_kernel<<<dim3(32, 4), 256, 0, stream>>>(pnum, pden, Wo, out);
}

// Round 6
// 90.103 us; speedup vs baseline: 1.5268x; 1.2832x over previous
//
#include <hip/hip_runtime.h>

// Problem constants
#define L_SEQ 2048
#define NH 2
#define FD 16
#define BH 8            // B * H
#define NQT 8           // 256-query tiles
#define NSC 16          // 128-key chunks

typedef _Float16 half4f __attribute__((ext_vector_type(4)));
typedef float floatx4 __attribute__((ext_vector_type(4)));

struct FalseT { static constexpr bool value = false; };
struct TrueT  { static constexpr bool value = true;  };

// ---------------- Kernel A: fused QKV projection (f16 out, q pre-scaled) ----------------
__global__ __launch_bounds__(256) void qkv_proj_kernel(
    const float* __restrict__ hs, const float* __restrict__ Wq,
    const float* __restrict__ Wk, const float* __restrict__ Wv,
    _Float16* __restrict__ q, _Float16* __restrict__ k,
    _Float16* __restrict__ v) {
  __shared__ float sW[3][32][32];
  __shared__ float sH[32][32];
  int tid = threadIdx.x;
  float* swf = &sW[0][0][0];
  for (int i = tid; i < 3072; i += 256)
    swf[i] = (i < 1024) ? Wq[i] : (i < 2048) ? Wk[i - 1024] : Wv[i - 2048];
  int row0 = blockIdx.x * 32;
  int r0 = tid >> 5, c = tid & 31;
  for (int p = 0; p < 4; p++) {
    int r = r0 + p * 8;
    sH[r][c] = hs[(size_t)(row0 + r) * 32 + c];
  }
  __syncthreads();
  int hh = c >> 4, f = c & 15;
  for (int p = 0; p < 4; p++) {
    int r = r0 + p * 8;
    float aq = 0.f, ak = 0.f, av = 0.f;
#pragma unroll
    for (int i = 0; i < 32; i++) {
      float h = sH[r][i];
      aq += h * sW[0][i][c];
      ak += h * sW[1][i][c];
      av += h * sW[2][i][c];
    }
    int row = row0 + r;
    int b = row >> 11, l = row & (L_SEQ - 1);
    size_t idx = (((size_t)(b * NH + hh)) * L_SEQ + l) * FD + f;
    q[idx] = (_Float16)(aq * 0.25f);  // fold 1/sqrt(d)
    k[idx] = (_Float16)ak;
    v[idx] = (_Float16)av;
  }
}

// ---------------- Kernel B: MFMA partial attention ----------------
// Block x -> (qt, sc) with sc <= 2qt+1; y = bh. 256 threads = 4 waves,
// wave w owns queries [qt*256 + w*64, +64) as 4 16x16 subtiles.
// Swapped QK: S^T = mfma(K_tile, Q^T) puts (q=lane&15, s=4*(lane>>4)+reg)
// in-lane == exactly the A-frag layout for the PV mfma. No shuffles.
__global__ __launch_bounds__(256) void attn_partial_kernel(
    const _Float16* __restrict__ q, const _Float16* __restrict__ k,
    const _Float16* __restrict__ v, float* __restrict__ pnum,
    float* __restrict__ pden) {
  __shared__ _Float16 sK[128][24];    // row-pad 24: conflict-light b64 reads
  __shared__ _Float16 sVT[16][136];   // V transposed, pad 136
  int tid = threadIdx.x;
  int bh = blockIdx.y;
  int x = blockIdx.x;
  int qt = 0;
  while ((qt + 1) * (qt + 2) <= x) qt++;
  int sc = x - qt * (qt + 1);

  {  // stage K rows + V^T
    int s = tid >> 1, h = tid & 1;
    const _Float16* kp = k + ((size_t)bh * L_SEQ + sc * 128 + s) * FD + 8 * h;
    const _Float16* vp = v + ((size_t)bh * L_SEQ + sc * 128 + s) * FD + 8 * h;
    uint4 kw = *(const uint4*)kp;
    *(uint4*)&sK[s][8 * h] = kw;
    union { uint4 u; _Float16 e[8]; } vu;
    vu.u = *(const uint4*)vp;
#pragma unroll
    for (int i = 0; i < 8; i++) sVT[8 * h + i][s] = vu.e[i];
  }

  int lane = tid & 63;
  int wid = tid >> 6;
  int lm = lane & 15, lg = lane >> 4;

  half4f qf[4];  // B-frag: Q[q=lm][f=4*lg..+3] per subtile
  {
    const _Float16* qb = q + ((size_t)bh * L_SEQ + qt * 256 + wid * 64) * FD;
#pragma unroll
    for (int sub = 0; sub < 4; sub++)
      qf[sub] = *(const half4f*)(qb + (sub * 16 + lm) * FD + 4 * lg);
  }
  floatx4 o[4];
  float dn[4];
#pragma unroll
  for (int i = 0; i < 4; i++) {
    o[i] = (floatx4){0.f, 0.f, 0.f, 0.f};
    dn[i] = 0.f;
  }
  int tq[4];
#pragma unroll
  for (int sub = 0; sub < 4; sub++) tq[sub] = qt * 256 + wid * 64 + sub * 16 + lm;
  int sb = sc * 128 + 4 * lg;

  __syncthreads();

  auto body = [&](auto mc) {
    constexpr bool MASK = decltype(mc)::value;
#pragma unroll
    for (int st = 0; st < 8; st++) {
      half4f kf = *(const half4f*)&sK[st * 16 + lm][4 * lg];      // A: K[s=lm][f]
      half4f vf = *(const half4f*)&sVT[lm][st * 16 + 4 * lg];     // B: V[s][f=lm]
#pragma unroll
      for (int sub = 0; sub < 4; sub++) {
        floatx4 sT = __builtin_amdgcn_mfma_f32_16x16x16f16(
            kf, qf[sub], (floatx4){0.f, 0.f, 0.f, 0.f}, 0, 0, 0);
        float wvv[4];
#pragma unroll
        for (int r = 0; r < 4; r++) {
          float a = sT[r];
          float wr = (0.5f * a + 1.f) * a + 1.f;  // 1 + g + g^2/2
          if (MASK) wr = (sb + st * 16 + r <= tq[sub]) ? wr : 0.f;
          wvv[r] = wr;
          dn[sub] += wr;
        }
        half4f wf = {(_Float16)wvv[0], (_Float16)wvv[1],
                     (_Float16)wvv[2], (_Float16)wvv[3]};
        o[sub] = __builtin_amdgcn_mfma_f32_16x16x16f16(wf, vf, o[sub], 0, 0, 0);
      }
    }
  };
  if (sc < 2 * qt) body(FalseT{}); else body(TrueT{});

#pragma unroll
  for (int sub = 0; sub < 4; sub++) {
    dn[sub] += __shfl_xor(dn[sub], 16, 64);
    dn[sub] += __shfl_xor(dn[sub], 32, 64);
  }

  size_t pb = ((size_t)(bh * NQT + qt) * NSC + sc) * 256;
  float* nb = pnum + (pb + wid * 64) * 16;
#pragma unroll
  for (int sub = 0; sub < 4; sub++)
#pragma unroll
    for (int r = 0; r < 4; r++)
      nb[(sub * 16 + 4 * lg + r) * 16 + lm] = o[sub][r];
  if (lg == 0) {
#pragma unroll
    for (int sub = 0; sub < 4; sub++)
      pden[pb + wid * 64 + sub * 16 + lm] = dn[sub];
  }
}

// ---------------- Kernel C: reduce partials + output projection ----------------
__global__ __launch_bounds__(256) void reduce_outproj_kernel(
    const float* __restrict__ pnum, const float* __restrict__ pden,
    const float* __restrict__ Wo, float* __restrict__ out) {
  __shared__ float sY[64][33];
  __shared__ float sWo[32][32];
  int tid = threadIdx.x;
  for (int i = tid; i < 1024; i += 256) (&sWo[0][0])[i] = Wo[i];

  int ql = tid >> 2, fq = tid & 3;
  int t = blockIdx.x * 64 + ql;
  int b = blockIdx.y;
  int qt = t >> 8;   // 256-query tile
  int scm = t >> 7;  // max s-chunk (inclusive)
  int qloc = t & 255;

  for (int h = 0; h < NH; h++) {
    int bh = b * NH + h;
    size_t tb = ((size_t)(bh * NQT + qt) * NSC) * 256;
    const float* nb = pnum + (tb + qloc) * 16 + fq * 4;
    const float* db = pden + tb + qloc;
    float a0 = 0.f, a1 = 0.f, a2 = 0.f, a3 = 0.f, den = 0.f;
    for (int sc = 0; sc <= scm; sc++) {
      float4 p = *(const float4*)(nb + (size_t)sc * 256 * 16);
      a0 += p.x; a1 += p.y; a2 += p.z; a3 += p.w;
      den += db[(size_t)sc * 256];
    }
    float inv = 1.f / den;
    int cb = h * 16 + fq * 4;
    sY[ql][cb + 0] = a0 * inv;
    sY[ql][cb + 1] = a1 * inv;
    sY[ql][cb + 2] = a2 * inv;
    sY[ql][cb + 3] = a3 * inv;
  }
  __syncthreads();

  int c = tid & 31, r0 = tid >> 5;
  float wo[32];
#pragma unroll
  for (int i = 0; i < 32; i++) wo[i] = sWo[i][c];
#pragma unroll
  for (int p = 0; p < 8; p++) {
    int r = r0 + p * 8;
    float a = 0.f;
#pragma unroll
    for (int i = 0; i < 32; i++) a += sY[r][i] * wo[i];
    out[((size_t)b * L_SEQ + blockIdx.x * 64 + r) * 32 + c] = a;
  }
}

extern "C" void kernel_launch(void* const* d_in, const int* in_sizes, int n_in,
                              void* d_out, int out_size, void* d_ws, size_t ws_size,
                              hipStream_t stream) {
  const float* hs = (const float*)d_in[0];
  const float* Wq = (const float*)d_in[1];
  const float* Wk = (const float*)d_in[2];
  const float* Wv = (const float*)d_in[3];
  const float* Wo = (const float*)d_in[4];
  float* out = (float*)d_out;

  char* wb = (char*)d_ws;
  const size_t PER = (size_t)BH * L_SEQ * FD;  // 262144 elements
  _Float16* qh = (_Float16*)wb;
  _Float16* kh = qh + PER;
  _Float16* vh = kh + PER;
  float* pnum = (float*)(wb + 3 * PER * sizeof(_Float16));  // 16.8 MB
  float* pden = pnum + (size_t)BH * NQT * NSC * 256 * 16;   // 1 MB

  qkv_proj_kernel<<<256, 256, 0, stream>>>(hs, Wq, Wk, Wv, qh, kh, vh);
  attn_partial_kernel<<<dim3(72, BH), 256, 0, stream>>>(qh, kh, vh, pnum, pden);
  reduce_outproj_kernel<<<dim3(32, 4), 256, 0, stream>>>(pnum, pden, Wo, out);
}

// Round 7
// 90.069 us; speedup vs baseline: 1.5274x; 1.0004x over previous
//
#include <hip/hip_runtime.h>

// Problem constants
#define L_SEQ 2048
#define NH 2
#define FD 16
#define BH 8            // B * H
#define NQT 16          // 128-query tiles
#define NSC 16          // 128-key chunks

typedef _Float16 half4f __attribute__((ext_vector_type(4)));
typedef float floatx4 __attribute__((ext_vector_type(4)));

struct FalseT { static constexpr bool value = false; };
struct TrueT  { static constexpr bool value = true;  };

// ---------------- Kernel A: fused QKV projection (f16 out, q pre-scaled) ----------------
__global__ __launch_bounds__(256) void qkv_proj_kernel(
    const float* __restrict__ hs, const float* __restrict__ Wq,
    const float* __restrict__ Wk, const float* __restrict__ Wv,
    _Float16* __restrict__ q, _Float16* __restrict__ k,
    _Float16* __restrict__ v) {
  __shared__ float sW[3][32][32];
  __shared__ float sH[32][32];
  int tid = threadIdx.x;
  float* swf = &sW[0][0][0];
  for (int i = tid; i < 3072; i += 256)
    swf[i] = (i < 1024) ? Wq[i] : (i < 2048) ? Wk[i - 1024] : Wv[i - 2048];
  int row0 = blockIdx.x * 32;
  int r0 = tid >> 5, c = tid & 31;
  for (int p = 0; p < 4; p++) {
    int r = r0 + p * 8;
    sH[r][c] = hs[(size_t)(row0 + r) * 32 + c];
  }
  __syncthreads();
  int hh = c >> 4, f = c & 15;
  for (int p = 0; p < 4; p++) {
    int r = r0 + p * 8;
    float aq = 0.f, ak = 0.f, av = 0.f;
#pragma unroll
    for (int i = 0; i < 32; i++) {
      float h = sH[r][i];
      aq += h * sW[0][i][c];
      ak += h * sW[1][i][c];
      av += h * sW[2][i][c];
    }
    int row = row0 + r;
    int b = row >> 11, l = row & (L_SEQ - 1);
    size_t idx = (((size_t)(b * NH + hh)) * L_SEQ + l) * FD + f;
    q[idx] = (_Float16)(aq * 0.25f);  // fold 1/sqrt(d)
    k[idx] = (_Float16)ak;
    v[idx] = (_Float16)av;
  }
}

// ---------------- Kernel B: MFMA partial attention ----------------
// Block x in [0,136) -> (qt, sc) with sc <= qt (triangular); y = bh.
// 256 threads = 4 waves; wave w owns queries [qt*128 + w*32, +32) as two
// 16x16 subtiles. Swapped QK: S^T = mfma(K, Q^T) puts (q=lane&15,
// s=4*(lane>>4)+r) in-lane == exactly the A-frag layout for the PV mfma.
__global__ __launch_bounds__(256) void attn_partial_kernel(
    const _Float16* __restrict__ q, const _Float16* __restrict__ k,
    const _Float16* __restrict__ v, float* __restrict__ pnum,
    float* __restrict__ pden) {
  __shared__ _Float16 sK[128][24];    // row-pad 24: conflict-light b64 reads
  __shared__ _Float16 sVT[16][136];   // V transposed, pad 136
  int tid = threadIdx.x;
  int bh = blockIdx.y;
  int x = blockIdx.x;
  int qt = 0;
  while ((qt + 1) * (qt + 2) / 2 <= x) qt++;   // triangular decode
  int sc = x - qt * (qt + 1) / 2;

  {  // stage K rows + V^T
    int s = tid >> 1, h = tid & 1;
    const _Float16* kp = k + ((size_t)bh * L_SEQ + sc * 128 + s) * FD + 8 * h;
    const _Float16* vp = v + ((size_t)bh * L_SEQ + sc * 128 + s) * FD + 8 * h;
    uint4 kw = *(const uint4*)kp;
    *(uint4*)&sK[s][8 * h] = kw;
    union { uint4 u; _Float16 e[8]; } vu;
    vu.u = *(const uint4*)vp;
#pragma unroll
    for (int i = 0; i < 8; i++) sVT[8 * h + i][s] = vu.e[i];
  }

  int lane = tid & 63;
  int wid = tid >> 6;
  int lm = lane & 15, lg = lane >> 4;

  half4f qf[2];  // B-frag: Q[q=lm][f=4*lg..+3] per subtile
  {
    const _Float16* qb = q + ((size_t)bh * L_SEQ + qt * 128 + wid * 32) * FD;
#pragma unroll
    for (int sub = 0; sub < 2; sub++)
      qf[sub] = *(const half4f*)(qb + (sub * 16 + lm) * FD + 4 * lg);
  }
  floatx4 o[2];
  float dn[2];
#pragma unroll
  for (int i = 0; i < 2; i++) {
    o[i] = (floatx4){0.f, 0.f, 0.f, 0.f};
    dn[i] = 0.f;
  }
  int tq[2];
#pragma unroll
  for (int sub = 0; sub < 2; sub++)
    tq[sub] = qt * 128 + wid * 32 + sub * 16 + lm;
  int sb = sc * 128 + 4 * lg;

  __syncthreads();

  auto body = [&](auto mc) {
    constexpr bool MASK = decltype(mc)::value;
#pragma unroll
    for (int st = 0; st < 8; st++) {
      half4f kf = *(const half4f*)&sK[st * 16 + lm][4 * lg];      // A: K[s=lm][f]
      half4f vf = *(const half4f*)&sVT[lm][st * 16 + 4 * lg];     // B: V[s][f=lm]
#pragma unroll
      for (int sub = 0; sub < 2; sub++) {
        floatx4 sT = __builtin_amdgcn_mfma_f32_16x16x16f16(
            kf, qf[sub], (floatx4){0.f, 0.f, 0.f, 0.f}, 0, 0, 0);
        float wvv[4];
#pragma unroll
        for (int r = 0; r < 4; r++) {
          float a = sT[r];
          float wr = (0.5f * a + 1.f) * a + 1.f;  // 1 + g + g^2/2
          if (MASK) wr = (sb + st * 16 + r <= tq[sub]) ? wr : 0.f;
          wvv[r] = wr;
          dn[sub] += wr;
        }
        half4f wf = {(_Float16)wvv[0], (_Float16)wvv[1],
                     (_Float16)wvv[2], (_Float16)wvv[3]};
        o[sub] = __builtin_amdgcn_mfma_f32_16x16x16f16(wf, vf, o[sub], 0, 0, 0);
      }
    }
  };
  if (sc < qt) body(FalseT{}); else body(TrueT{});

#pragma unroll
  for (int sub = 0; sub < 2; sub++) {
    dn[sub] += __shfl_xor(dn[sub], 16, 64);
    dn[sub] += __shfl_xor(dn[sub], 32, 64);
  }

  // pnum: [bh][qt][sc][q 128][16], pden: [bh][qt][sc][q 128]
  size_t pb = ((size_t)(bh * NQT + qt) * NSC + sc) * 128;
  float* nb = pnum + (pb + wid * 32) * 16;
#pragma unroll
  for (int sub = 0; sub < 2; sub++)
#pragma unroll
    for (int r = 0; r < 4; r++)
      nb[(sub * 16 + 4 * lg + r) * 16 + lm] = o[sub][r];
  if (lg == 0) {
#pragma unroll
    for (int sub = 0; sub < 2; sub++)
      pden[pb + wid * 32 + sub * 16 + lm] = dn[sub];
  }
}

// ---------------- Kernel C: reduce partials + output projection ----------------
__global__ __launch_bounds__(256) void reduce_outproj_kernel(
    const float* __restrict__ pnum, const float* __restrict__ pden,
    const float* __restrict__ Wo, float* __restrict__ out) {
  __shared__ float sY[64][33];
  __shared__ float sWo[32][32];
  int tid = threadIdx.x;
  for (int i = tid; i < 1024; i += 256) (&sWo[0][0])[i] = Wo[i];

  int ql = tid >> 2, fq = tid & 3;
  int t = blockIdx.x * 64 + ql;
  int b = blockIdx.y;
  int qt = t >> 7;   // 128-query tile; also max s-chunk (inclusive)
  int qloc = t & 127;

  for (int h = 0; h < NH; h++) {
    int bh = b * NH + h;
    size_t tb = ((size_t)(bh * NQT + qt) * NSC) * 128;
    const float* nb = pnum + (tb + qloc) * 16 + fq * 4;
    const float* db = pden + tb + qloc;
    float a0 = 0.f, a1 = 0.f, a2 = 0.f, a3 = 0.f, den = 0.f;
    for (int sc = 0; sc <= qt; sc++) {
      float4 p = *(const float4*)(nb + (size_t)sc * 128 * 16);
      a0 += p.x; a1 += p.y; a2 += p.z; a3 += p.w;
      den += db[(size_t)sc * 128];
    }
    float inv = 1.f / den;
    int cb = h * 16 + fq * 4;
    sY[ql][cb + 0] = a0 * inv;
    sY[ql][cb + 1] = a1 * inv;
    sY[ql][cb + 2] = a2 * inv;
    sY[ql][cb + 3] = a3 * inv;
  }
  __syncthreads();

  int c = tid & 31, r0 = tid >> 5;
  float wo[32];
#pragma unroll
  for (int i = 0; i < 32; i++) wo[i] = sWo[i][c];
#pragma unroll
  for (int p = 0; p < 8; p++) {
    int r = r0 + p * 8;
    float a = 0.f;
#pragma unroll
    for (int i = 0; i < 32; i++) a += sY[r][i] * wo[i];
    out[((size_t)b * L_SEQ + blockIdx.x * 64 + r) * 32 + c] = a;
  }
}

extern "C" void kernel_launch(void* const* d_in, const int* in_sizes, int n_in,
                              void* d_out, int out_size, void* d_ws, size_t ws_size,
                              hipStream_t stream) {
  const float* hs = (const float*)d_in[0];
  const float* Wq = (const float*)d_in[1];
  const float* Wk = (const float*)d_in[2];
  const float* Wv = (const float*)d_in[3];
  const float* Wo = (const float*)d_in[4];
  float* out = (float*)d_out;

  char* wb = (char*)d_ws;
  const size_t PER = (size_t)BH * L_SEQ * FD;  // 262144 elements
  _Float16* qh = (_Float16*)wb;
  _Float16* kh = qh + PER;
  _Float16* vh = kh + PER;
  float* pnum = (float*)(wb + 3 * PER * sizeof(_Float16));  // 16 MB
  float* pden = pnum + (size_t)BH * NQT * NSC * 128 * 16;   // 1 MB

  qkv_proj_kernel<<<256, 256, 0, stream>>>(hs, Wq, Wk, Wv, qh, kh, vh);
  attn_partial_kernel<<<dim3(136, BH), 256, 0, stream>>>(qh, kh, vh, pnum, pden);
  reduce_outproj_kernel<<<dim3(32, 4), 256, 0, stream>>>(pnum, pden, Wo, out);
}

// Round 8
// 87.770 us; speedup vs baseline: 1.5674x; 1.0262x over previous
//
#include <hip/hip_runtime.h>

// Problem constants
#define L_SEQ 2048
#define NH 2
#define FD 16
#define BH 8            // B * H
#define QT 32           // queries per fused-attn block
#define NT 64           // q tiles (L_SEQ / QT)
#define SCW 128         // s per staged chunk

typedef _Float16 half4f __attribute__((ext_vector_type(4)));
typedef float floatx4 __attribute__((ext_vector_type(4)));

struct FalseT { static constexpr bool value = false; };
struct TrueT  { static constexpr bool value = true;  };

// ---------------- Kernel A: fused QKV projection (f16 out, q pre-scaled) ----------------
__global__ __launch_bounds__(256) void qkv_proj_kernel(
    const float* __restrict__ hs, const float* __restrict__ Wq,
    const float* __restrict__ Wk, const float* __restrict__ Wv,
    _Float16* __restrict__ q, _Float16* __restrict__ k,
    _Float16* __restrict__ v) {
  __shared__ float sW[3][32][32];
  __shared__ float sH[32][32];
  int tid = threadIdx.x;
  float* swf = &sW[0][0][0];
  for (int i = tid; i < 3072; i += 256)
    swf[i] = (i < 1024) ? Wq[i] : (i < 2048) ? Wk[i - 1024] : Wv[i - 2048];
  int row0 = blockIdx.x * 32;
  int r0 = tid >> 5, c = tid & 31;
  for (int p = 0; p < 4; p++) {
    int r = r0 + p * 8;
    sH[r][c] = hs[(size_t)(row0 + r) * 32 + c];
  }
  __syncthreads();
  int hh = c >> 4, f = c & 15;
  for (int p = 0; p < 4; p++) {
    int r = r0 + p * 8;
    float aq = 0.f, ak = 0.f, av = 0.f;
#pragma unroll
    for (int i = 0; i < 32; i++) {
      float h = sH[r][i];
      aq += h * sW[0][i][c];
      ak += h * sW[1][i][c];
      av += h * sW[2][i][c];
    }
    int row = row0 + r;
    int b = row >> 11, l = row & (L_SEQ - 1);
    size_t idx = (((size_t)(b * NH + hh)) * L_SEQ + l) * FD + f;
    q[idx] = (_Float16)(aq * 0.25f);  // fold 1/sqrt(d)
    k[idx] = (_Float16)ak;
    v[idx] = (_Float16)av;
  }
}

// ---------------- Kernel B: fused flash attention + output projection ----------------
// Block (xt, b): 32 queries [t*32, +32) of batch b, BOTH heads.
// Waves 0,1 -> head 0 subtiles 0,1; waves 2,3 -> head 1. Each wave loops the
// causal s-chunks online (no partials). Swapped QK as before:
// S^T = mfma(K, Q^T) -> lane holds (q=lm, s=16*st+4*lg+r) == A-frag for PV.
// Then den bounce via LDS, y/den -> sY, 32x32 out-proj with Wo.
__global__ __launch_bounds__(256) void attn_fused_kernel(
    const _Float16* __restrict__ q, const _Float16* __restrict__ k,
    const _Float16* __restrict__ v, const float* __restrict__ Wo,
    float* __restrict__ out) {
  __shared__ _Float16 sK[NH][128][24];
  __shared__ _Float16 sVT[NH][16][136];
  __shared__ float sDen[4][16];
  __shared__ float sY[QT][33];
  __shared__ float sWo[32][32];

  int tid = threadIdx.x;
  int b = blockIdx.y;
  int t = NT - 1 - (int)blockIdx.x;  // longest tiles first
  int lane = tid & 63;
  int wid = tid >> 6;
  int lm = lane & 15, lg = lane >> 4;
  int h = wid >> 1, sub = wid & 1;
  int bh = b * NH + h;

  for (int i = tid; i < 1024; i += 256) (&sWo[0][0])[i] = Wo[i];

  int q0 = t * QT + sub * 16;
  half4f qf = *(const half4f*)(q + ((size_t)bh * L_SEQ + q0 + lm) * FD + 4 * lg);

  floatx4 o = (floatx4){0.f, 0.f, 0.f, 0.f};
  float dn = 0.f;
  int tq = q0 + lm;            // this lane's query index
  int lastc = t >> 2;          // diagonal (masked) chunk
  int ss = tid >> 1, hf = tid & 1;

  auto body = [&](int sc, auto mc) {
    constexpr bool MASK = decltype(mc)::value;
    int sb = sc * SCW + 4 * lg;
#pragma unroll
    for (int st = 0; st < 8; st++) {
      half4f kf = *(const half4f*)&sK[h][st * 16 + lm][4 * lg];
      half4f vf = *(const half4f*)&sVT[h][lm][st * 16 + 4 * lg];
      floatx4 sT = __builtin_amdgcn_mfma_f32_16x16x16f16(
          kf, qf, (floatx4){0.f, 0.f, 0.f, 0.f}, 0, 0, 0);
      float wvv[4];
#pragma unroll
      for (int r = 0; r < 4; r++) {
        float a = sT[r];
        float wr = (0.5f * a + 1.f) * a + 1.f;  // 1 + g + g^2/2
        if (MASK) wr = (sb + st * 16 + r <= tq) ? wr : 0.f;
        wvv[r] = wr;
        dn += wr;
      }
      half4f wf = {(_Float16)wvv[0], (_Float16)wvv[1],
                   (_Float16)wvv[2], (_Float16)wvv[3]};
      o = __builtin_amdgcn_mfma_f32_16x16x16f16(wf, vf, o, 0, 0, 0);
    }
  };

  for (int sc = 0; sc <= lastc; sc++) {
    __syncthreads();  // previous chunk fully consumed
#pragma unroll
    for (int hh = 0; hh < NH; hh++) {
      const _Float16* kp =
          k + (((size_t)(b * NH + hh)) * L_SEQ + sc * SCW + ss) * FD + 8 * hf;
      const _Float16* vp =
          v + (((size_t)(b * NH + hh)) * L_SEQ + sc * SCW + ss) * FD + 8 * hf;
      *(uint4*)&sK[hh][ss][8 * hf] = *(const uint4*)kp;
      union { uint4 u; _Float16 e[8]; } vu;
      vu.u = *(const uint4*)vp;
#pragma unroll
      for (int i = 0; i < 8; i++) sVT[hh][8 * hf + i][ss] = vu.e[i];
    }
    __syncthreads();
    if (sc < lastc) body(sc, FalseT{}); else body(sc, TrueT{});
  }

  // denominator: sum over lg strips -> den[q=lm]; bounce via LDS to q=4lg+r lanes
  dn += __shfl_xor(dn, 16, 64);
  dn += __shfl_xor(dn, 32, 64);
  if (lg == 0) sDen[wid][lm] = dn;
  __syncthreads();
#pragma unroll
  for (int r = 0; r < 4; r++) {
    float dd = sDen[wid][4 * lg + r];
    sY[sub * 16 + 4 * lg + r][h * 16 + lm] = o[r] / dd;
  }
  __syncthreads();

  // out-proj: 32 rows x 32 cols
  int c = tid & 31, r0 = tid >> 5;
  float wo[32];
#pragma unroll
  for (int i = 0; i < 32; i++) wo[i] = sWo[i][c];
#pragma unroll
  for (int p = 0; p < 4; p++) {
    int r = r0 + p * 8;
    float a = 0.f;
#pragma unroll
    for (int i = 0; i < 32; i++) a += sY[r][i] * wo[i];
    out[((size_t)b * L_SEQ + t * QT + r) * 32 + c] = a;
  }
}

extern "C" void kernel_launch(void* const* d_in, const int* in_sizes, int n_in,
                              void* d_out, int out_size, void* d_ws, size_t ws_size,
                              hipStream_t stream) {
  const float* hs = (const float*)d_in[0];
  const float* Wq = (const float*)d_in[1];
  const float* Wk = (const float*)d_in[2];
  const float* Wv = (const float*)d_in[3];
  const float* Wo = (const float*)d_in[4];
  float* out = (float*)d_out;

  char* wb = (char*)d_ws;
  const size_t PER = (size_t)BH * L_SEQ * FD;  // 262144 elements
  _Float16* qh = (_Float16*)wb;
  _Float16* kh = qh + PER;
  _Float16* vh = kh + PER;

  qkv_proj_kernel<<<256, 256, 0, stream>>>(hs, Wq, Wk, Wv, qh, kh, vh);
  attn_fused_kernel<<<dim3(NT, 4), 256, 0, stream>>>(qh, kh, vh, Wo, out);
}